// Round 1
// baseline (380.324 us; speedup 1.0000x reference)
//
#include <hip/hip_runtime.h>
#include <hip/hip_bf16.h>

// Problem: SpatialAttentionLoss — B=8, S=12, H=W=512.
// Inputs (fp32, setup_inputs order):
//   d_in[0] seg_logits       [B,S,H,W]
//   d_in[1] seg_probs        [B,S,H,W]
//   d_in[2] presence_probs   [B,S]
//   d_in[3] attention_maps   [B,S,H,W]
//   d_in[4] seg_targets      [B,S,H,W]
//   d_in[5] presence_targets [B,S]
// Output: 7 fp32 scalars [total, seg, dice, absence, att, conf, fp].

constexpr int kB = 8, kS = 12, kH = 512, kW = 512;
constexpr int kSlices = kB * kS;          // 96
constexpr long kHW = (long)kH * kW;       // 262144 elements per slice
constexpr int kVecPerSlice = (int)(kHW / 4);  // 65536 float4
constexpr int kBlocksPerSlice = 32;
constexpr int kBlock = 256;
constexpr int kVecPerBlock = kVecPerSlice / kBlocksPerSlice;  // 2048
constexpr int kIters = kVecPerBlock / kBlock;                 // 8
constexpr float kEPS = 1e-6f;

// Per-slice accumulators layout in workspace: [96][6]
//   0: sum bce_with_logits(seg_logits, seg_targets)
//   1: sum seg_probs * seg_targets        (inter)
//   2: sum seg_probs                      (psum)
//   3: sum seg_targets                    (tsum)
//   4: sum max(seg_probs, 0)              (fp)
//   5: sum bce(attention_maps, tgt>0.5)   (att)

__global__ __launch_bounds__(kBlock) void slice_reduce_kernel(
    const float4* __restrict__ logits,
    const float4* __restrict__ probs,
    const float4* __restrict__ att,
    const float4* __restrict__ tgt,
    float* __restrict__ partial) {
  const int gid = blockIdx.x;
  const int slice = gid >> 5;                 // / kBlocksPerSlice
  const int chunk = gid & (kBlocksPerSlice - 1);
  const long base = (long)slice * kVecPerSlice + (long)chunk * kVecPerBlock
                    + threadIdx.x;

  float s_bce = 0.f, s_inter = 0.f, s_p = 0.f, s_t = 0.f, s_fp = 0.f,
        s_att = 0.f;

#pragma unroll
  for (int k = 0; k < kIters; ++k) {
    const long idx = base + (long)k * kBlock;
    const float4 x4 = logits[idx];
    const float4 p4 = probs[idx];
    const float4 a4 = att[idx];
    const float4 t4 = tgt[idx];
    const float xs[4] = {x4.x, x4.y, x4.z, x4.w};
    const float ps[4] = {p4.x, p4.y, p4.z, p4.w};
    const float as[4] = {a4.x, a4.y, a4.z, a4.w};
    const float ts[4] = {t4.x, t4.y, t4.z, t4.w};
#pragma unroll
    for (int j = 0; j < 4; ++j) {
      const float x = xs[j], p = ps[j], a = as[j], t = ts[j];
      // stable BCE-with-logits: max(x,0) - x*t + log1p(exp(-|x|))
      s_bce += fmaxf(x, 0.f) - x * t + log1pf(expf(-fabsf(x)));
      s_inter += p * t;
      s_p += p;
      s_t += t;
      s_fp += fmaxf(p, 0.f);
      // attention BCE with hard target (t is exactly 0.0 or 1.0)
      const float la = fmaxf(logf(a), -100.f);
      const float l1a = fmaxf(log1pf(-a), -100.f);
      s_att += (t > 0.5f) ? -la : -l1a;
    }
  }

  // block reduction: wave shuffle then cross-wave LDS
  float vals[6] = {s_bce, s_inter, s_p, s_t, s_fp, s_att};
  const int lane = threadIdx.x & 63;
  const int wave = threadIdx.x >> 6;
  __shared__ float lds[4][6];
#pragma unroll
  for (int q = 0; q < 6; ++q) {
    float v = vals[q];
    for (int off = 32; off > 0; off >>= 1) v += __shfl_down(v, off, 64);
    if (lane == 0) lds[wave][q] = v;
  }
  __syncthreads();
  if (threadIdx.x == 0) {
#pragma unroll
    for (int q = 0; q < 6; ++q) {
      const float v = lds[0][q] + lds[1][q] + lds[2][q] + lds[3][q];
      atomicAdd(&partial[slice * 6 + q], v);
    }
  }
}

__global__ __launch_bounds__(128) void finalize_kernel(
    const float* __restrict__ partial,
    const float* __restrict__ pprobs,
    const float* __restrict__ ptgt,
    float* __restrict__ out) {
  const int i = threadIdx.x;
  // quantities: 0 seg_bce*m, 1 dice*m, 2 fp*(1-m), 3 att*m, 4 absence_bce,
  //             5 conf, 6 maskf
  __shared__ float acc[7][128];
  float q[7] = {0.f, 0.f, 0.f, 0.f, 0.f, 0.f, 0.f};
  if (i < kSlices) {
    const float t = ptgt[i];
    const float m = (t != 0.f) ? 1.f : 0.f;
    const float inv = 1.f / (float)kHW;
    const float bce = partial[i * 6 + 0] * inv;
    const float inter = partial[i * 6 + 1];
    const float psum = partial[i * 6 + 2];
    const float tsum = partial[i * 6 + 3];
    const float fp = partial[i * 6 + 4] * inv;
    const float att = partial[i * 6 + 5] * inv;
    const float dice = 1.f - (2.f * inter + kEPS) / (psum + tsum + kEPS);
    q[0] = bce * m;
    q[1] = dice * m;
    q[2] = fp * (1.f - m);
    q[3] = att * m;
    const float p = pprobs[i];
    q[4] = -(t * fmaxf(logf(p), -100.f) +
             (1.f - t) * fmaxf(log1pf(-p), -100.f));
    float c = 0.f;
    if (t == 0.f && p > 0.5f) c += (p - 0.5f) * (p - 0.5f);
    if (t == 1.f && p < 0.5f) c += (0.5f - p) * (0.5f - p);
    q[5] = c;
    q[6] = m;
  }
#pragma unroll
  for (int k = 0; k < 7; ++k) acc[k][i] = q[k];
  __syncthreads();
  if (i == 0) {
    float s[7];
#pragma unroll
    for (int k = 0; k < 7; ++k) {
      float v = 0.f;
      for (int j = 0; j < kSlices; ++j) v += acc[k][j];
      s[k] = v;
    }
    const float n_valid = s[6];
    const float n_absent = (float)kSlices - n_valid;
    const float seg_loss = (n_valid > 0.f) ? s[0] / fmaxf(n_valid, 1.f) : 0.f;
    const float dice_loss = (n_valid > 0.f) ? s[1] / fmaxf(n_valid, 1.f) : 0.f;
    const float fp_loss = (n_absent > 0.f) ? s[2] / fmaxf(n_absent, 1.f) : 0.f;
    const float att_loss = s[3] / (float)kSlices;
    const float absence_loss = s[4] / (float)kSlices;
    const float conf_loss = s[5] / (float)kSlices;
    const float total = 1.0f * seg_loss + 1.0f * dice_loss +
                        2.0f * absence_loss + 0.3f * att_loss +
                        0.1f * conf_loss + 0.5f * fp_loss;
    out[0] = total;
    out[1] = seg_loss;
    out[2] = dice_loss;
    out[3] = absence_loss;
    out[4] = att_loss;
    out[5] = conf_loss;
    out[6] = fp_loss;
  }
}

extern "C" void kernel_launch(void* const* d_in, const int* in_sizes, int n_in,
                              void* d_out, int out_size, void* d_ws,
                              size_t ws_size, hipStream_t stream) {
  const float4* seg_logits = (const float4*)d_in[0];
  const float4* seg_probs = (const float4*)d_in[1];
  const float* presence_probs = (const float*)d_in[2];
  const float4* attention_maps = (const float4*)d_in[3];
  const float4* seg_targets = (const float4*)d_in[4];
  const float* presence_targets = (const float*)d_in[5];
  float* out = (float*)d_out;
  float* partial = (float*)d_ws;

  // zero the 96x6 partial-sum workspace (harness poisons d_ws to 0xAA)
  hipMemsetAsync(partial, 0, kSlices * 6 * sizeof(float), stream);

  slice_reduce_kernel<<<kSlices * kBlocksPerSlice, kBlock, 0, stream>>>(
      seg_logits, seg_probs, attention_maps, seg_targets, partial);
  finalize_kernel<<<1, 128, 0, stream>>>(partial, presence_probs,
                                         presence_targets, out);
}

// Round 2
// 343.015 us; speedup vs baseline: 1.1088x; 1.1088x over previous
//
#include <hip/hip_runtime.h>
#include <hip/hip_bf16.h>

// Problem: SpatialAttentionLoss — B=8, S=12, H=W=512.
// Inputs (fp32, setup_inputs order):
//   d_in[0] seg_logits       [B,S,H,W]
//   d_in[1] seg_probs        [B,S,H,W]
//   d_in[2] presence_probs   [B,S]
//   d_in[3] attention_maps   [B,S,H,W]
//   d_in[4] seg_targets      [B,S,H,W]
//   d_in[5] presence_targets [B,S]
// Output: 7 fp32 scalars [total, seg, dice, absence, att, conf, fp].

constexpr int kB = 8, kS = 12, kH = 512, kW = 512;
constexpr int kSlices = kB * kS;          // 96
constexpr long kHW = (long)kH * kW;       // 262144 elements per slice
constexpr int kVecPerSlice = (int)(kHW / 4);  // 65536 float4
constexpr int kBlocksPerSlice = 32;
constexpr int kBlock = 256;
constexpr int kVecPerBlock = kVecPerSlice / kBlocksPerSlice;  // 2048
constexpr int kIters = kVecPerBlock / kBlock;                 // 8
constexpr float kEPS = 1e-6f;
constexpr float kLOG2E = 1.44269504088896340736f;
constexpr float kLN2 = 0.69314718055994530942f;

// Per-block partial slot layout in workspace: partial[gid][6], gid = slice*32+chunk
//   0: sum bce_with_logits(seg_logits, seg_targets)
//   1: sum seg_probs * seg_targets        (inter)
//   2: sum seg_probs                      (psum)
//   3: sum seg_targets                    (tsum)
//   4: sum max(seg_probs, 0)              (fp)
//   5: sum bce(attention_maps, tgt>0.5)   (att)

__global__ __launch_bounds__(kBlock) void slice_reduce_kernel(
    const float4* __restrict__ logits,
    const float4* __restrict__ probs,
    const float4* __restrict__ att,
    const float4* __restrict__ tgt,
    float* __restrict__ partial) {
  const int gid = blockIdx.x;
  const int slice = gid >> 5;                 // / kBlocksPerSlice
  const int chunk = gid & (kBlocksPerSlice - 1);
  const long base = (long)slice * kVecPerSlice + (long)chunk * kVecPerBlock
                    + threadIdx.x;

  float s_bce = 0.f, s_inter = 0.f, s_p = 0.f, s_t = 0.f, s_fp = 0.f,
        s_att = 0.f;

#pragma unroll
  for (int k = 0; k < kIters; ++k) {
    const long idx = base + (long)k * kBlock;
    const float4 x4 = logits[idx];
    const float4 p4 = probs[idx];
    const float4 a4 = att[idx];
    const float4 t4 = tgt[idx];
    const float xs[4] = {x4.x, x4.y, x4.z, x4.w};
    const float ps[4] = {p4.x, p4.y, p4.z, p4.w};
    const float as[4] = {a4.x, a4.y, a4.z, a4.w};
    const float ts[4] = {t4.x, t4.y, t4.z, t4.w};
#pragma unroll
    for (int j = 0; j < 4; ++j) {
      const float x = xs[j], p = ps[j], a = as[j], t = ts[j];
      // stable BCE-with-logits: max(x,0) - x*t + ln(1 + 2^(-|x|*log2e))
      // u = exp(-|x|) in (0,1] so 1+u in (1,2] is exact; hw log is log2.
      const float u = __builtin_amdgcn_exp2f(-fabsf(x) * kLOG2E);
      s_bce += fmaxf(x, 0.f) - x * t +
               kLN2 * __builtin_amdgcn_logf(1.f + u);
      s_inter += p * t;
      s_p += p;
      s_t += t;
      s_fp += fmaxf(p, 0.f);
      // attention BCE with hard target (t is exactly 0.0 or 1.0):
      // select operand first, then ONE hw log.
      // a in [1e-6, 1-1e-6]; for a>0.5, 1-a is exact (Sterbenz).
      const float c = (t > 0.5f) ? a : 1.0f - a;
      s_att -= kLN2 * __builtin_amdgcn_logf(c);
    }
  }

  // block reduction: wave shuffle then cross-wave LDS
  float vals[6] = {s_bce, s_inter, s_p, s_t, s_fp, s_att};
  const int lane = threadIdx.x & 63;
  const int wave = threadIdx.x >> 6;
  __shared__ float lds[4][6];
#pragma unroll
  for (int q = 0; q < 6; ++q) {
    float v = vals[q];
    for (int off = 32; off > 0; off >>= 1) v += __shfl_down(v, off, 64);
    if (lane == 0) lds[wave][q] = v;
  }
  __syncthreads();
  if (threadIdx.x == 0) {
#pragma unroll
    for (int q = 0; q < 6; ++q) {
      // private slot per block: no atomics, no memset dispatch needed
      partial[gid * 6 + q] = lds[0][q] + lds[1][q] + lds[2][q] + lds[3][q];
    }
  }
}

__global__ __launch_bounds__(128) void finalize_kernel(
    const float* __restrict__ partial,
    const float* __restrict__ pprobs,
    const float* __restrict__ ptgt,
    float* __restrict__ out) {
  const int i = threadIdx.x;
  // quantities: 0 seg_bce*m, 1 dice*m, 2 fp*(1-m), 3 att*m, 4 absence_bce,
  //             5 conf, 6 maskf
  __shared__ float acc[7][128];
  float q[7] = {0.f, 0.f, 0.f, 0.f, 0.f, 0.f, 0.f};
  if (i < kSlices) {
    // fold this slice's 32 chunk-partials
    float s[6] = {0.f, 0.f, 0.f, 0.f, 0.f, 0.f};
    for (int c = 0; c < kBlocksPerSlice; ++c) {
      const float* row = &partial[(i * kBlocksPerSlice + c) * 6];
#pragma unroll
      for (int k = 0; k < 6; ++k) s[k] += row[k];
    }
    const float t = ptgt[i];
    const float m = (t != 0.f) ? 1.f : 0.f;
    const float inv = 1.f / (float)kHW;
    const float bce = s[0] * inv;
    const float inter = s[1];
    const float psum = s[2];
    const float tsum = s[3];
    const float fp = s[4] * inv;
    const float attv = s[5] * inv;
    const float dice = 1.f - (2.f * inter + kEPS) / (psum + tsum + kEPS);
    q[0] = bce * m;
    q[1] = dice * m;
    q[2] = fp * (1.f - m);
    q[3] = attv * m;
    const float p = pprobs[i];
    q[4] = -(t * fmaxf(logf(p), -100.f) +
             (1.f - t) * fmaxf(log1pf(-p), -100.f));
    float c = 0.f;
    if (t == 0.f && p > 0.5f) c += (p - 0.5f) * (p - 0.5f);
    if (t == 1.f && p < 0.5f) c += (0.5f - p) * (0.5f - p);
    q[5] = c;
    q[6] = m;
  }
#pragma unroll
  for (int k = 0; k < 7; ++k) acc[k][i] = q[k];
  __syncthreads();
  if (i == 0) {
    float s[7];
#pragma unroll
    for (int k = 0; k < 7; ++k) {
      float v = 0.f;
      for (int j = 0; j < kSlices; ++j) v += acc[k][j];
      s[k] = v;
    }
    const float n_valid = s[6];
    const float n_absent = (float)kSlices - n_valid;
    const float seg_loss = (n_valid > 0.f) ? s[0] / fmaxf(n_valid, 1.f) : 0.f;
    const float dice_loss = (n_valid > 0.f) ? s[1] / fmaxf(n_valid, 1.f) : 0.f;
    const float fp_loss = (n_absent > 0.f) ? s[2] / fmaxf(n_absent, 1.f) : 0.f;
    const float att_loss = s[3] / (float)kSlices;
    const float absence_loss = s[4] / (float)kSlices;
    const float conf_loss = s[5] / (float)kSlices;
    const float total = 1.0f * seg_loss + 1.0f * dice_loss +
                        2.0f * absence_loss + 0.3f * att_loss +
                        0.1f * conf_loss + 0.5f * fp_loss;
    out[0] = total;
    out[1] = seg_loss;
    out[2] = dice_loss;
    out[3] = absence_loss;
    out[4] = att_loss;
    out[5] = conf_loss;
    out[6] = fp_loss;
  }
}

extern "C" void kernel_launch(void* const* d_in, const int* in_sizes, int n_in,
                              void* d_out, int out_size, void* d_ws,
                              size_t ws_size, hipStream_t stream) {
  const float4* seg_logits = (const float4*)d_in[0];
  const float4* seg_probs = (const float4*)d_in[1];
  const float* presence_probs = (const float*)d_in[2];
  const float4* attention_maps = (const float4*)d_in[3];
  const float4* seg_targets = (const float4*)d_in[4];
  const float* presence_targets = (const float*)d_in[5];
  float* out = (float*)d_out;
  float* partial = (float*)d_ws;  // [3072][6] floats, fully overwritten

  slice_reduce_kernel<<<kSlices * kBlocksPerSlice, kBlock, 0, stream>>>(
      seg_logits, seg_probs, attention_maps, seg_targets, partial);
  finalize_kernel<<<1, 128, 0, stream>>>(partial, presence_probs,
                                         presence_targets, out);
}